// Round 5
// baseline (785.779 us; speedup 1.0000x reference)
//
#include <hip/hip_runtime.h>
#include <hip/hip_bf16.h>
#include <math.h>

// CircumpunctSSM: B=4, T=512, D=1024, S=16, dt_rank=64. All f32.
// Pipeline:
//   g1: siluxz[2048,2048] = silu(x @ W_in.T)   [128x128 tile]
//   g2: xp[2048,128]      = x_in @ W_xproj.T   [64x64 tile]
//   g3: dt[2048,1024]     = softplus(xp[:, :64] @ W_dt.T + b_dt) [64x64]
//   g4: xc[2048,32]       = x_in @ W_res.T     [64x64]
//   scan (64 blocks = B*S, 512 thr x 2 elems = D): h recurrence + comp mean; y -> private partials
//   reduce_y: ybuf = sum_s ypart[s]
//   g5: out = (y * silu(z)) @ W_out.T + b_out  [128x128 tile]

enum { EPI_NONE=0, EPI_SILU=1, EPI_SPBIAS=2, EPI_BIAS=3 };

template<int EPI>
__device__ __forceinline__ float epi_apply(float v, float b) {
  if constexpr (EPI == EPI_SILU)        { return v / (1.0f + expf(-v)); }
  else if constexpr (EPI == EPI_SPBIAS) { float t = v + b; return fmaxf(t, 0.0f) + log1pf(expf(-fabsf(t))); }
  else if constexpr (EPI == EPI_BIAS)   { return v + b; }
  else return v;
}

// ---------------- 64x64 tile (small N: g2/g3/g4) ----------------
template<int EPI, bool HAS_A2>
__global__ __launch_bounds__(256) void gemm_wt(
    const float* __restrict__ A, int lda,
    const float* __restrict__ A2, int lda2,
    const float* __restrict__ W, int ldw,
    const float* __restrict__ bias,
    float* __restrict__ C, int ldc,
    int N, int K)
{
  constexpr int BM = 64, BN = 64, BK = 16, PAD = 4;
  __shared__ float As[BK][BM + PAD];
  __shared__ float Ws[BK][BN + PAD];
  const int m0 = blockIdx.x * BM;
  const int n0 = blockIdx.y * BN;
  const int tid = threadIdx.x;
  const int tx = tid & 15;
  const int ty = tid >> 4;
  const int lm = tid >> 2;
  const int lk = (tid & 3) << 2;

  float acc[4][4] = {{0.f,0.f,0.f,0.f},{0.f,0.f,0.f,0.f},{0.f,0.f,0.f,0.f},{0.f,0.f,0.f,0.f}};

  for (int k0 = 0; k0 < K; k0 += BK) {
    float4 av, wv;
    {
      const float* p = A + (size_t)(m0 + lm) * lda + k0 + lk;
      av = *(const float4*)p;
      if (HAS_A2) {
        const float4 a2 = *(const float4*)(A2 + (size_t)(m0 + lm) * lda2 + k0 + lk);
        av.x *= a2.x; av.y *= a2.y; av.z *= a2.z; av.w *= a2.w;
      }
    }
    {
      const int n = n0 + lm;
      if (n < N) wv = *(const float4*)(W + (size_t)n * ldw + k0 + lk);
      else       wv = make_float4(0.f, 0.f, 0.f, 0.f);
    }
    __syncthreads();
    As[lk+0][lm] = av.x; As[lk+1][lm] = av.y; As[lk+2][lm] = av.z; As[lk+3][lm] = av.w;
    Ws[lk+0][lm] = wv.x; Ws[lk+1][lm] = wv.y; Ws[lk+2][lm] = wv.z; Ws[lk+3][lm] = wv.w;
    __syncthreads();
#pragma unroll
    for (int kk = 0; kk < BK; ++kk) {
      const float4 a = *(const float4*)&As[kk][ty << 2];
      const float4 w = *(const float4*)&Ws[kk][tx << 2];
      const float ar[4] = {a.x, a.y, a.z, a.w};
      const float wr[4] = {w.x, w.y, w.z, w.w};
#pragma unroll
      for (int i = 0; i < 4; ++i)
#pragma unroll
        for (int j = 0; j < 4; ++j)
          acc[i][j] = fmaf(ar[i], wr[j], acc[i][j]);
    }
  }

  const int ncol = n0 + (tx << 2);
  float bj[4] = {0.f, 0.f, 0.f, 0.f};
  if constexpr (EPI == EPI_SPBIAS || EPI == EPI_BIAS) {
    if (ncol < N) { const float4 bv = *(const float4*)(bias + ncol); bj[0]=bv.x; bj[1]=bv.y; bj[2]=bv.z; bj[3]=bv.w; }
  }
  if (ncol < N) {
#pragma unroll
    for (int i = 0; i < 4; ++i) {
      float vs[4];
#pragma unroll
      for (int j = 0; j < 4; ++j) vs[j] = epi_apply<EPI>(acc[i][j], bj[j]);
      *(float4*)(C + (size_t)(m0 + (ty << 2) + i) * ldc + ncol) = make_float4(vs[0], vs[1], vs[2], vs[3]);
    }
  }
}

// ---------------- 128x128 tile (big GEMMs: g1/g5) ----------------
// 256 thr, 8x8 acc/thread, BK=16. 4x arithmetic intensity and 4x fewer
// barriers per FLOP vs the 64x64 tile. M,N multiples of 128 here.
template<int EPI, bool HAS_A2>
__global__ __launch_bounds__(256) void gemm_wt128(
    const float* __restrict__ A, int lda,
    const float* __restrict__ A2, int lda2,
    const float* __restrict__ W, int ldw,
    const float* __restrict__ bias,
    float* __restrict__ C, int ldc,
    int N, int K)
{
  constexpr int BM = 128, BN = 128, BK = 16, PAD = 4;
  __shared__ float As[BK][BM + PAD];
  __shared__ float Ws[BK][BN + PAD];
  const int m0 = blockIdx.x * BM;
  const int n0 = blockIdx.y * BN;
  const int tid = threadIdx.x;
  const int tx = tid & 15;        // n-dir, 8 cols each
  const int ty = tid >> 4;        // m-dir, 8 rows each
  const int lm = tid >> 1;        // 0..127 staging row
  const int lk = (tid & 1) << 3;  // 0 or 8 (two float4)

  float acc[8][8];
#pragma unroll
  for (int i = 0; i < 8; ++i)
#pragma unroll
    for (int j = 0; j < 8; ++j) acc[i][j] = 0.f;

  for (int k0 = 0; k0 < K; k0 += BK) {
    float4 av0, av1, wv0, wv1;
    {
      const float* p = A + (size_t)(m0 + lm) * lda + k0 + lk;
      av0 = ((const float4*)p)[0]; av1 = ((const float4*)p)[1];
      if (HAS_A2) {
        const float* p2 = A2 + (size_t)(m0 + lm) * lda2 + k0 + lk;
        const float4 b0 = ((const float4*)p2)[0], b1 = ((const float4*)p2)[1];
        av0.x*=b0.x; av0.y*=b0.y; av0.z*=b0.z; av0.w*=b0.w;
        av1.x*=b1.x; av1.y*=b1.y; av1.z*=b1.z; av1.w*=b1.w;
      }
    }
    {
      const int n = n0 + lm;
      if (n < N) {
        const float* p = W + (size_t)n * ldw + k0 + lk;
        wv0 = ((const float4*)p)[0]; wv1 = ((const float4*)p)[1];
      } else {
        wv0 = make_float4(0.f,0.f,0.f,0.f); wv1 = wv0;
      }
    }
    __syncthreads();
    As[lk+0][lm]=av0.x; As[lk+1][lm]=av0.y; As[lk+2][lm]=av0.z; As[lk+3][lm]=av0.w;
    As[lk+4][lm]=av1.x; As[lk+5][lm]=av1.y; As[lk+6][lm]=av1.z; As[lk+7][lm]=av1.w;
    Ws[lk+0][lm]=wv0.x; Ws[lk+1][lm]=wv0.y; Ws[lk+2][lm]=wv0.z; Ws[lk+3][lm]=wv0.w;
    Ws[lk+4][lm]=wv1.x; Ws[lk+5][lm]=wv1.y; Ws[lk+6][lm]=wv1.z; Ws[lk+7][lm]=wv1.w;
    __syncthreads();
#pragma unroll
    for (int kk = 0; kk < BK; ++kk) {
      const float4 a0 = *(const float4*)&As[kk][ty << 3];
      const float4 a1 = *(const float4*)&As[kk][(ty << 3) + 4];
      const float4 w0 = *(const float4*)&Ws[kk][tx << 3];
      const float4 w1 = *(const float4*)&Ws[kk][(tx << 3) + 4];
      const float ar[8] = {a0.x,a0.y,a0.z,a0.w,a1.x,a1.y,a1.z,a1.w};
      const float wr[8] = {w0.x,w0.y,w0.z,w0.w,w1.x,w1.y,w1.z,w1.w};
#pragma unroll
      for (int i = 0; i < 8; ++i)
#pragma unroll
        for (int j = 0; j < 8; ++j)
          acc[i][j] = fmaf(ar[i], wr[j], acc[i][j]);
    }
  }

  const int ncol = n0 + (tx << 3);
  float bj[8] = {0.f,0.f,0.f,0.f,0.f,0.f,0.f,0.f};
  if constexpr (EPI == EPI_SPBIAS || EPI == EPI_BIAS) {
    if (ncol < N) {
      const float4 b0 = *(const float4*)(bias + ncol);
      const float4 b1 = *(const float4*)(bias + ncol + 4);
      bj[0]=b0.x; bj[1]=b0.y; bj[2]=b0.z; bj[3]=b0.w;
      bj[4]=b1.x; bj[5]=b1.y; bj[6]=b1.z; bj[7]=b1.w;
    }
  }
  if (ncol < N) {
#pragma unroll
    for (int i = 0; i < 8; ++i) {
      float vs[8];
#pragma unroll
      for (int j = 0; j < 8; ++j) vs[j] = epi_apply<EPI>(acc[i][j], bj[j]);
      float* pc = C + (size_t)(m0 + (ty << 3) + i) * ldc + ncol;
      *(float4*)pc       = make_float4(vs[0], vs[1], vs[2], vs[3]);
      *(float4*)(pc + 4) = make_float4(vs[4], vs[5], vs[6], vs[7]);
    }
  }
}

__global__ void zero_kernel(float4* __restrict__ p, int n4) {
  const int i = blockIdx.x * blockDim.x + threadIdx.x;
  if (i < n4) p[i] = make_float4(0.f, 0.f, 0.f, 0.f);
}

// ybuf[i] = sum_s ypart[s][i]  (i over B*T*D float4s; per-s chunk = 524288 float4)
__global__ __launch_bounds__(256) void reduce_y(const float4* __restrict__ yp, float4* __restrict__ yo, int n4) {
  const int i = blockIdx.x * blockDim.x + threadIdx.x;
  if (i >= n4) return;
  float4 a = yp[i];
#pragma unroll
  for (int s = 1; s < 16; ++s) {
    const float4 v = yp[(size_t)s * 524288 + i];
    a.x += v.x; a.y += v.y; a.z += v.z; a.w += v.w;
  }
  yo[i] = a;
}

// --- DPP wave64 sum: 6 dependent full-rate VALU adds. Lane 63 ends with the
// --- full 64-lane sum (only lane 63's value is consumed).
template<int CTRL>
__device__ __forceinline__ float dpp_fadd(float x) {
  const int s = __builtin_amdgcn_update_dpp(0, __float_as_int(x), CTRL, 0xF, 0xF, true);
  return x + __int_as_float(s);
}
__device__ __forceinline__ float wave64_sum_l63(float x) {
  x = dpp_fadd<0x111>(x);   // row_shr:1
  x = dpp_fadd<0x112>(x);   // row_shr:2
  x = dpp_fadd<0x114>(x);   // row_shr:4
  x = dpp_fadd<0x118>(x);   // row_shr:8
  x = dpp_fadd<0x142>(x);   // row_bcast:15
  x = dpp_fadd<0x143>(x);   // row_bcast:31
  return x;                 // lane 63 = full sum
}

// Scan: one block per (b,s); 512 threads x 2 consecutive d each (8 waves,
// 2 waves/SIMD). R5: at 4 waves (1/SIMD) every chain stall (ds_read ~120cy,
// barrier wake, transcendental latency) was exposed — no co-resident wave to
// fill it. 8 waves keeps per-SIMD issue work identical (block work is fixed)
// but lets the second wave on each SIMD fill the stalls: step ~ max(issue,
// chain) instead of issue + chain. DPP reduce, rotated d-update, depth-2
// prefetch, lgkm-only raw barrier all unchanged from R4.
template<bool PARTIAL>
__global__ __launch_bounds__(512) void scan_kernel(
    const float* __restrict__ xin,   // siluxz base, ld 2048 (cols 0..1023 = x_in)
    const float* __restrict__ xp,    // ld 128
    const float* __restrict__ dtb,   // ld 1024
    const float* __restrict__ xc,    // ld 32
    const float* __restrict__ A_log, // [16]
    float* __restrict__ ybase,       // PARTIAL ? ypart[16][B*T*D] : y (pre-zeroed), ld 1024
    int T)
{
  const int b = blockIdx.x >> 4;
  const int s = blockIdx.x & 15;
  const int d0 = threadIdx.x << 1;          // 2 consecutive d per thread
  const int lane = threadIdx.x & 63;
  const int wid = threadIdx.x >> 6;         // 0..7

  __shared__ __align__(16) float red[3][8][2];  // [buf][wave][r,i]
  if (threadIdx.x < 48) ((float*)red)[threadIdx.x] = 0.f;  // all 3 buffers zeroed

  const float a_s = expf(A_log[s]);
  const float phase = (float)(6.283185307179586 * (double)s / 16.0);
  float d_r = 0.01f * cosf(phase);
  float d_i = 0.01f * sinf(phase);
  float h_r[2] = {0.f,0.f};
  float h_i[2] = {0.f,0.f};
  __syncthreads();

  // per-thread walking pointers (one row per step)
  const size_t rb = (size_t)b * T;
  const float* px  = xin + rb * 2048 + d0;
  const float* pdt = dtb + rb * 1024 + d0;
  const float* pB  = xp  + rb * 128 + 64 + 2 * s;
  const float* pC  = xp  + rb * 128 + 96 + 2 * s;
  const float* pxc = xc  + rb * 32 + 2 * s;
  float* py = PARTIAL ? (ybase + (size_t)s * (4 * 512 * 1024) + rb * 1024 + d0)
                      : (ybase + rb * 1024 + d0);

  // preload rows t=0 (cur) and t=1 (nxt)
  float2 xv   = *(const float2*)px;
  float2 dtv  = *(const float2*)pdt;
  float2 Bv   = *(const float2*)pB;
  float2 Cv   = *(const float2*)pC;
  float2 xcv  = *(const float2*)pxc;
  float2 xvn  = *(const float2*)(px + 2048);
  float2 dtvn = *(const float2*)(pdt + 1024);
  float2 Bvn  = *(const float2*)(pB + 128);
  float2 Cvn  = *(const float2*)(pC + 128);
  float2 xcvn = *(const float2*)(pxc + 32);

  int cb = 0, pb = 2;  // write buffer t%3, read buffer (t-1)%3 (t=0 reads zeros)

  for (int t = 0; t < T; ++t) {
    // 1. prefetch t+2 (longest possible lead over consumption)
    //    (At t>=T-2 these read <=2 rows past each logical buffer; all land
    //     inside the workspace allocation and the values are never used.)
    const float2 xv2  = *(const float2*)(px + 2 * 2048);
    const float2 dtv2 = *(const float2*)(pdt + 2 * 1024);
    const float2 Bv2  = *(const float2*)(pB + 2 * 128);
    const float2 Cv2  = *(const float2*)(pC + 2 * 128);
    const float2 xcv2 = *(const float2*)(pxc + 2 * 32);

    // 2. read previous step's wave partials (latency hidden under comp below)
    const float4 q0 = *(const float4*)&red[pb][0][0];
    const float4 q1 = *(const float4*)&red[pb][2][0];
    const float4 q2 = *(const float4*)&red[pb][4][0];
    const float4 q3 = *(const float4*)&red[pb][6][0];

    // 3. comp from released(h_prev, alpha) — independent of d
    const float xa[2]  = {xv.x, xv.y};
    const float dta[2] = {dtv.x, dtv.y};
    float alpha[2];
    float w_r = 0.f, w_i = 0.f;
#pragma unroll
    for (int e = 0; e < 2; ++e) {
      alpha[e] = __expf(-dta[e] * a_s);
      const float om    = 1.0f - alpha[e];
      const float rel_r = h_r[e] * om, rel_i = h_i[e] * om;
      const float m2 = fmaf(rel_r, rel_r, fmaf(rel_i, rel_i, 1e-8f));
      const float cm = exp2f(log2f(m2) * (1.0f / 3.0f));     // mag^(2/3)
      const float rr = rel_r + 1e-10f;
      const float invr = __builtin_amdgcn_rsqf(fmaf(rr, rr, fmaf(rel_i, rel_i, 1e-38f)));
      float c_r = cm * rr * invr;    c_r = fminf(fmaxf(c_r, -10.f), 10.f);
      float c_i = cm * rel_i * invr; c_i = fminf(fmaxf(c_i, -10.f), 10.f);
      w_r += c_r; w_i += c_i;
    }
    // wave sum via DPP (full-rate VALU); lane 63 holds the total
    w_r = wave64_sum_l63(w_r);
    w_i = wave64_sum_l63(w_i);
    if (lane == 63) *(float2*)&red[cb][wid][0] = make_float2(w_r, w_i);

    // 4. d update from PREVIOUS step's comp mean; clip to |d|<=20
    const float avg_r = (q0.x + q0.z + q1.x + q1.z + q2.x + q2.z + q3.x + q3.z) * (1.0f / 1024.0f);
    const float avg_i = (q0.y + q0.w + q1.y + q1.w + q2.y + q2.w + q3.y + q3.w) * (1.0f / 1024.0f);
    d_r = fmaf(0.01f, avg_r, d_r);
    d_i = fmaf(0.01f, avg_i, d_i);
    const float dm2c = fmaf(d_r, d_r, fmaf(d_i, d_i, 1e-8f));
    if (dm2c > 400.f) { const float sc = 20.f * __builtin_amdgcn_rsqf(dm2c); d_r *= sc; d_i *= sc; }

    // 5. surfaced from d (== reference d_prev for this step) + x_complex
    const float xr2 = xcv.x + 1e-10f;
    const float irx = __builtin_amdgcn_rsqf(fmaf(xr2, xr2, fmaf(xcv.y, xcv.y, 1e-38f)));
    const float dr2 = d_r + 1e-10f;
    const float ird = __builtin_amdgcn_rsqf(fmaf(dr2, dr2, fmaf(d_i, d_i, 1e-38f)));
    const float cosdp = fmaf(xr2, dr2, xcv.y * d_i) * irx * ird;
    const float Tg  = 0.5f * (1.0f + cosdp);                  // cos^2((phix-phid)/2)
    const float md2  = fmaf(d_r, d_r, fmaf(d_i, d_i, 1e-8f));
    const float irm  = __builtin_amdgcn_rsqf(md2);
    const float dmag = md2 * irm;                             // sqrt(md2)
    const float cl   = fminf(fmaxf(dmag, 1e-6f), 20.f);
    const float dscale = cl * __builtin_amdgcn_rsqf(cl);      // sqrt(cl)
    const float sfac = dscale * Tg * __builtin_amdgcn_rcpf(dmag + 1e-8f);
    const float s_r = d_r * sfac, s_i = d_i * sfac;

    // 6. h update + y contribution
    float yv[2];
#pragma unroll
    for (int e = 0; e < 2; ++e) {
      const float bx_r = fmaf(Bv.x, xa[e], s_r) * dta[e];
      const float bx_i = fmaf(Bv.y, xa[e], s_i) * dta[e];
      h_r[e] = fmaf(h_r[e], alpha[e], bx_r);
      h_i[e] = fmaf(h_i[e], alpha[e], bx_i);
      yv[e] = fmaf(Cv.x, h_r[e], -(Cv.y * h_i[e]));
    }
    if (PARTIAL) {
      *(float2*)py = make_float2(yv[0], yv[1]);   // private buffer, no contention
    } else {
      atomicAdd(py + 0, yv[0]);
      atomicAdd(py + 1, yv[1]);
    }

    // 7. raw barrier: drain LDS ops only; global loads/stores stay in flight
    asm volatile("s_waitcnt lgkmcnt(0)" ::: "memory");
    __builtin_amdgcn_s_barrier();
    asm volatile("" ::: "memory");

    // rotate prefetched rows and buffers, advance pointers
    xv = xvn; dtv = dtvn; Bv = Bvn; Cv = Cvn; xcv = xcvn;
    xvn = xv2; dtvn = dtv2; Bvn = Bv2; Cvn = Cv2; xcvn = xcv2;
    px += 2048; pdt += 1024; pB += 128; pC += 128; pxc += 32; py += 1024;
    pb = cb; cb = (cb == 2) ? 0 : cb + 1;
  }
}

extern "C" void kernel_launch(void* const* d_in, const int* in_sizes, int n_in,
                              void* d_out, int out_size, void* d_ws, size_t ws_size,
                              hipStream_t stream) {
  const float* x     = (const float*)d_in[0];
  const float* W_in  = (const float*)d_in[1];
  const float* W_xp  = (const float*)d_in[2];
  const float* W_dt  = (const float*)d_in[3];
  const float* b_dt  = (const float*)d_in[4];
  const float* W_out = (const float*)d_in[5];
  const float* b_out = (const float*)d_in[6];
  const float* W_res = (const float*)d_in[7];
  const float* A_log = (const float*)d_in[8];
  float* out = (float*)d_out;

  float* ws     = (float*)d_ws;
  float* siluxz = ws;                               // 2048*2048   = 4,194,304 f
  float* xp     = siluxz + (size_t)2048 * 2048;     // 2048*128    =   262,144 f
  float* dtb    = xp     + (size_t)2048 * 128;      // 2048*1024   = 2,097,152 f
  float* xc     = dtb    + (size_t)2048 * 1024;     // 2048*32     =    65,536 f
  float* ybuf   = xc     + (size_t)2048 * 32;       // 2048*1024   = 2,097,152 f
  float* ypart  = ybuf   + (size_t)2048 * 1024;     // 16*2048*1024 = 33,554,432 f (if it fits)

  const size_t need_bytes = ((size_t)8716288 + (size_t)33554432) * 4;  // base + ypart
  const bool use_part = ws_size >= need_bytes;

  // g1: siluxz = silu(x @ W_in.T)   M=2048 N=2048 K=1024  [128x128]
  gemm_wt128<EPI_SILU, false><<<dim3(16, 16), 256, 0, stream>>>(
      x, 1024, nullptr, 0, W_in, 1024, nullptr, siluxz, 2048, 2048, 1024);
  // g2: xp = x_in @ W_xproj.T       N=128 K=1024
  gemm_wt<EPI_NONE, false><<<dim3(32, 2), 256, 0, stream>>>(
      siluxz, 2048, nullptr, 0, W_xp, 1024, nullptr, xp, 128, 128, 1024);
  // g3: dt = softplus(xp[:, :64] @ W_dt.T + b_dt)  N=1024 K=64
  gemm_wt<EPI_SPBIAS, false><<<dim3(32, 16), 256, 0, stream>>>(
      xp, 128, nullptr, 0, W_dt, 64, b_dt, dtb, 1024, 1024, 64);
  // g4: xc = x_in @ W_res.T         N=32 K=1024
  gemm_wt<EPI_NONE, false><<<dim3(32, 1), 256, 0, stream>>>(
      siluxz, 2048, nullptr, 0, W_res, 1024, nullptr, xc, 32, 32, 1024);

  if (use_part) {
    // scan writes private partials (plain stores); then fold over s
    scan_kernel<true><<<dim3(64), dim3(512), 0, stream>>>(
        siluxz, xp, dtb, xc, A_log, ypart, 512);
    reduce_y<<<dim3(2048), 256, 0, stream>>>((const float4*)ypart, (float4*)ybuf, 524288);
  } else {
    // fallback: atomic accumulation into pre-zeroed ybuf
    zero_kernel<<<dim3(2048), 256, 0, stream>>>((float4*)ybuf, (2048 * 1024) / 4);
    scan_kernel<false><<<dim3(64), dim3(512), 0, stream>>>(
        siluxz, xp, dtb, xc, A_log, ybuf, 512);
  }

  // g5: out = (y * silu(z)) @ W_out.T + b_out   N=1024 K=1024  [128x128]
  gemm_wt128<EPI_BIAS, true><<<dim3(16, 8), 256, 0, stream>>>(
      ybuf, 1024, siluxz + 1024, 2048, W_out, 1024, b_out, out, 1024, 1024, 1024);
}

// Round 6
// 640.672 us; speedup vs baseline: 1.2265x; 1.2265x over previous
//
#include <hip/hip_runtime.h>
#include <hip/hip_bf16.h>
#include <math.h>

// CircumpunctSSM: B=4, T=512, D=1024, S=16, dt_rank=64. All f32.
// Pipeline:
//   g1: siluxz[2048,2048] = silu(x @ W_in.T)
//   g2: xp[2048,128]      = x_in @ W_xproj.T
//   g3: dt[2048,1024]     = softplus(xp[:, :64] @ W_dt.T + b_dt)
//   g4: xc[2048,32]       = x_in @ W_res.T
//   scan (64 blocks = B*S, 256 thr x 4 elems): 2 time-steps per barrier period
//   reduce_y: ybuf = sum_s ypart[s]
//   g5: out = (y * silu(z)) @ W_out.T + b_out

enum { EPI_NONE=0, EPI_SILU=1, EPI_SPBIAS=2, EPI_BIAS=3 };

template<int EPI>
__device__ __forceinline__ float epi_apply(float v, float b) {
  if constexpr (EPI == EPI_SILU)        { return v / (1.0f + expf(-v)); }
  else if constexpr (EPI == EPI_SPBIAS) { float t = v + b; return fmaxf(t, 0.0f) + log1pf(expf(-fabsf(t))); }
  else if constexpr (EPI == EPI_BIAS)   { return v + b; }
  else return v;
}

// ---------------- 64x64 tile GEMM (all five GEMMs; 128x128 variant regressed in R5) ----
template<int EPI, bool HAS_A2>
__global__ __launch_bounds__(256) void gemm_wt(
    const float* __restrict__ A, int lda,
    const float* __restrict__ A2, int lda2,
    const float* __restrict__ W, int ldw,
    const float* __restrict__ bias,
    float* __restrict__ C, int ldc,
    int N, int K)
{
  constexpr int BM = 64, BN = 64, BK = 16, PAD = 4;
  __shared__ float As[BK][BM + PAD];
  __shared__ float Ws[BK][BN + PAD];
  const int m0 = blockIdx.x * BM;
  const int n0 = blockIdx.y * BN;
  const int tid = threadIdx.x;
  const int tx = tid & 15;
  const int ty = tid >> 4;
  const int lm = tid >> 2;
  const int lk = (tid & 3) << 2;

  float acc[4][4] = {{0.f,0.f,0.f,0.f},{0.f,0.f,0.f,0.f},{0.f,0.f,0.f,0.f},{0.f,0.f,0.f,0.f}};

  for (int k0 = 0; k0 < K; k0 += BK) {
    float4 av, wv;
    {
      const float* p = A + (size_t)(m0 + lm) * lda + k0 + lk;
      av = *(const float4*)p;
      if (HAS_A2) {
        const float4 a2 = *(const float4*)(A2 + (size_t)(m0 + lm) * lda2 + k0 + lk);
        av.x *= a2.x; av.y *= a2.y; av.z *= a2.z; av.w *= a2.w;
      }
    }
    {
      const int n = n0 + lm;
      if (n < N) wv = *(const float4*)(W + (size_t)n * ldw + k0 + lk);
      else       wv = make_float4(0.f, 0.f, 0.f, 0.f);
    }
    __syncthreads();
    As[lk+0][lm] = av.x; As[lk+1][lm] = av.y; As[lk+2][lm] = av.z; As[lk+3][lm] = av.w;
    Ws[lk+0][lm] = wv.x; Ws[lk+1][lm] = wv.y; Ws[lk+2][lm] = wv.z; Ws[lk+3][lm] = wv.w;
    __syncthreads();
#pragma unroll
    for (int kk = 0; kk < BK; ++kk) {
      const float4 a = *(const float4*)&As[kk][ty << 2];
      const float4 w = *(const float4*)&Ws[kk][tx << 2];
      const float ar[4] = {a.x, a.y, a.z, a.w};
      const float wr[4] = {w.x, w.y, w.z, w.w};
#pragma unroll
      for (int i = 0; i < 4; ++i)
#pragma unroll
        for (int j = 0; j < 4; ++j)
          acc[i][j] = fmaf(ar[i], wr[j], acc[i][j]);
    }
  }

  const int ncol = n0 + (tx << 2);
  float bj[4] = {0.f, 0.f, 0.f, 0.f};
  if constexpr (EPI == EPI_SPBIAS || EPI == EPI_BIAS) {
    if (ncol < N) { const float4 bv = *(const float4*)(bias + ncol); bj[0]=bv.x; bj[1]=bv.y; bj[2]=bv.z; bj[3]=bv.w; }
  }
  if (ncol < N) {
#pragma unroll
    for (int i = 0; i < 4; ++i) {
      float vs[4];
#pragma unroll
      for (int j = 0; j < 4; ++j) vs[j] = epi_apply<EPI>(acc[i][j], bj[j]);
      *(float4*)(C + (size_t)(m0 + (ty << 2) + i) * ldc + ncol) = make_float4(vs[0], vs[1], vs[2], vs[3]);
    }
  }
}

__global__ void zero_kernel(float4* __restrict__ p, int n4) {
  const int i = blockIdx.x * blockDim.x + threadIdx.x;
  if (i < n4) p[i] = make_float4(0.f, 0.f, 0.f, 0.f);
}

// ybuf[i] = sum_s ypart[s][i]
__global__ __launch_bounds__(256) void reduce_y(const float4* __restrict__ yp, float4* __restrict__ yo, int n4) {
  const int i = blockIdx.x * blockDim.x + threadIdx.x;
  if (i >= n4) return;
  float4 a = yp[i];
#pragma unroll
  for (int s = 1; s < 16; ++s) {
    const float4 v = yp[(size_t)s * 524288 + i];
    a.x += v.x; a.y += v.y; a.z += v.z; a.w += v.w;
  }
  yo[i] = a;
}

// --- DPP wave64 sum: 6 dependent full-rate VALU adds. Lane 63 ends with the
// --- full 64-lane sum (only lane 63's value is consumed).
template<int CTRL>
__device__ __forceinline__ float dpp_fadd(float x) {
  const int s = __builtin_amdgcn_update_dpp(0, __float_as_int(x), CTRL, 0xF, 0xF, true);
  return x + __int_as_float(s);
}
__device__ __forceinline__ float wave64_sum_l63(float x) {
  x = dpp_fadd<0x111>(x);   // row_shr:1
  x = dpp_fadd<0x112>(x);   // row_shr:2
  x = dpp_fadd<0x114>(x);   // row_shr:4
  x = dpp_fadd<0x118>(x);   // row_shr:8
  x = dpp_fadd<0x142>(x);   // row_bcast:15
  x = dpp_fadd<0x143>(x);   // row_bcast:31
  return x;                 // lane 63 = full sum
}

// comp for one row (given dt row and current h); also outputs alpha for that row.
// Returns wave-partial sums (lane 63 of wr/wi after DPP).
__device__ __forceinline__ void comp_block(const float4& dtv, const float a_s,
    const float (&h_r)[4], const float (&h_i)[4], float (&al_out)[4],
    float& wr, float& wi)
{
  const float ta[4] = {dtv.x, dtv.y, dtv.z, dtv.w};
  float sr = 0.f, si = 0.f;
#pragma unroll
  for (int e = 0; e < 4; ++e) {
    const float a = __expf(-ta[e] * a_s);
    al_out[e] = a;
    const float om    = 1.0f - a;
    const float rel_r = h_r[e] * om, rel_i = h_i[e] * om;
    const float m2 = fmaf(rel_r, rel_r, fmaf(rel_i, rel_i, 1e-8f));
    const float cm = exp2f(log2f(m2) * (1.0f / 3.0f));     // mag^(2/3)
    const float rr = rel_r + 1e-10f;
    const float invr = __builtin_amdgcn_rsqf(fmaf(rr, rr, fmaf(rel_i, rel_i, 1e-38f)));
    float cr = cm * rr * invr;    cr = fminf(fmaxf(cr, -10.f), 10.f);
    float ci = cm * rel_i * invr; ci = fminf(fmaxf(ci, -10.f), 10.f);
    sr += cr; si += ci;
  }
  wr = wave64_sum_l63(sr);
  wi = wave64_sum_l63(si);
}

// One time-step: d += 0.01*avg (pre-averaged), clip; surfaced; h update; y out.
template<bool PARTIAL>
__device__ __forceinline__ void step_update(
    float& d_r, float& d_i, const float avg_r, const float avg_i,
    const float2& cx, const float4& xv, const float4& dtv,
    const float2& Bv, const float2& Cv,
    const float (&alv)[4], float (&h_r)[4], float (&h_i)[4],
    float* py)
{
  d_r = fmaf(0.01f, avg_r, d_r);
  d_i = fmaf(0.01f, avg_i, d_i);
  const float dm2c = fmaf(d_r, d_r, fmaf(d_i, d_i, 1e-8f));
  if (dm2c > 400.f) { const float sc = 20.f * __builtin_amdgcn_rsqf(dm2c); d_r *= sc; d_i *= sc; }

  const float xr2 = cx.x + 1e-10f;
  const float irx = __builtin_amdgcn_rsqf(fmaf(xr2, xr2, fmaf(cx.y, cx.y, 1e-38f)));
  const float dr2 = d_r + 1e-10f;
  const float ird = __builtin_amdgcn_rsqf(fmaf(dr2, dr2, fmaf(d_i, d_i, 1e-38f)));
  const float cosdp = fmaf(xr2, dr2, cx.y * d_i) * irx * ird;
  const float Tg  = 0.5f * (1.0f + cosdp);
  const float md2  = fmaf(d_r, d_r, fmaf(d_i, d_i, 1e-8f));
  const float irm  = __builtin_amdgcn_rsqf(md2);
  const float dmag = md2 * irm;
  const float cl   = fminf(fmaxf(dmag, 1e-6f), 20.f);
  const float dsc  = cl * __builtin_amdgcn_rsqf(cl);
  const float sf   = dsc * Tg * __builtin_amdgcn_rcpf(dmag + 1e-8f);
  const float s_r = d_r * sf, s_i = d_i * sf;

  const float xa[4] = {xv.x, xv.y, xv.z, xv.w};
  const float ta[4] = {dtv.x, dtv.y, dtv.z, dtv.w};
  float yv[4];
#pragma unroll
  for (int e = 0; e < 4; ++e) {
    const float bx_r = fmaf(Bv.x, xa[e], s_r) * ta[e];
    const float bx_i = fmaf(Bv.y, xa[e], s_i) * ta[e];
    h_r[e] = fmaf(h_r[e], alv[e], bx_r);
    h_i[e] = fmaf(h_i[e], alv[e], bx_i);
    yv[e] = fmaf(Cv.x, h_r[e], -(Cv.y * h_i[e]));
  }
  if (PARTIAL) {
    *(float4*)py = make_float4(yv[0], yv[1], yv[2], yv[3]);
  } else {
#pragma unroll
    for (int e = 0; e < 4; ++e) atomicAdd(py + e, yv[e]);
  }
}

// One barrier PERIOD = two time-steps (rows RO, RO+1) + comp for row RO+2.
// Semantics identical to the per-step schedule: the d-sequence consumes
// avg(comp(t-1)) exactly one step late, which gives enough slack to compute
// comp one step ahead and exchange TWO partial sums per barrier.
// Slot0 = row RO (fully consumed; refilled <- RO+3), slot1 = row RO+1
// (refilled <- RO+4), t2 = dt of row RO+2 (read-only here).
template<int RB, int RO, bool PARTIAL>
__device__ __forceinline__ void period_body(
    const float* __restrict__ px, const float* __restrict__ pdt,
    const float* __restrict__ pB, const float* __restrict__ pC,
    const float* __restrict__ pxc, float* __restrict__ py,
    const float a_s, const int lane, const int wid,
    float (*red)[4][4],
    float& d_r, float& d_i,
    float (&h_r)[4], float (&h_i)[4], float (&al)[4],
    float4& x0, float4& t0, float2& B0, float2& C0, float2& c0,
    float4& x1, float4& t1, float2& B1, float2& C1, float2& c1,
    const float4& t2)
{
  // phase 1: read previous period's partials {P(2k-1) in .x/.y, P(2k) in .z/.w}
  const float4 qa = *(const float4*)&red[RB][0][0];
  const float4 qb = *(const float4*)&red[RB][1][0];
  const float4 qc = *(const float4*)&red[RB][2][0];
  const float4 qd = *(const float4*)&red[RB][3][0];

  // phases 2+3: even step (row RO) using odd partial
  step_update<PARTIAL>(d_r, d_i,
      (qa.x + qb.x + qc.x + qd.x) * (1.0f / 1024.0f),
      (qa.y + qb.y + qc.y + qd.y) * (1.0f / 1024.0f),
      c0, x0, t0, B0, C0, al, h_r, h_i, py + (size_t)RO * 1024);

  // refill slot0 <- row RO+3 (issued right after last use; stays in flight
  // across the barrier; consumed next period — OOB-safe at the tail, lands
  // inside the workspace and values are unused)
  x0 = *(const float4*)(px  + (size_t)(RO + 3) * 2048);
  t0 = *(const float4*)(pdt + (size_t)(RO + 3) * 1024);
  B0 = *(const float2*)(pB  + (RO + 3) * 128);
  C0 = *(const float2*)(pC  + (RO + 3) * 128);
  c0 = *(const float2*)(pxc + (RO + 3) * 32);

  // phase 4: comp for odd row (RO+1) from h(RO); also yields alpha(RO+1)
  float al1[4], w1r, w1i;
  comp_block(t1, a_s, h_r, h_i, al1, w1r, w1i);

  // phases 5+6: odd step (row RO+1) using even partial
  step_update<PARTIAL>(d_r, d_i,
      (qa.z + qb.z + qc.z + qd.z) * (1.0f / 1024.0f),
      (qa.w + qb.w + qc.w + qd.w) * (1.0f / 1024.0f),
      c1, x1, t1, B1, C1, al1, h_r, h_i, py + (size_t)(RO + 1) * 1024);

  // refill slot1 <- row RO+4
  x1 = *(const float4*)(px  + (size_t)(RO + 4) * 2048);
  t1 = *(const float4*)(pdt + (size_t)(RO + 4) * 1024);
  B1 = *(const float2*)(pB  + (RO + 4) * 128);
  C1 = *(const float2*)(pC  + (RO + 4) * 128);
  c1 = *(const float2*)(pxc + (RO + 4) * 32);

  // phase 7: comp for next even row (RO+2) from h(RO+1); alpha carried out in al
  float w2r, w2i;
  comp_block(t2, a_s, h_r, h_i, al, w2r, w2i);

  // phase 8: one ds_write_b128 carries BOTH partials
  if (lane == 63) *(float4*)&red[(RB + 1) % 3][wid][0] = make_float4(w1r, w1i, w2r, w2i);

  // phase 9: raw barrier — LDS-only drain; global loads/stores stay in flight
  asm volatile("s_waitcnt lgkmcnt(0)" ::: "memory");
  __builtin_amdgcn_s_barrier();
  asm volatile("" ::: "memory");
}

// Scan: one block per (b,s); 256 threads x 4 consecutive d each (4 waves).
// R6: two time-steps per barrier (see period_body). 3-period unrolled loop
// rotates the three row-slots with zero register copies.
template<bool PARTIAL>
__global__ __launch_bounds__(256) void scan_kernel(
    const float* __restrict__ xin,   // siluxz base, ld 2048 (cols 0..1023 = x_in)
    const float* __restrict__ xp,    // ld 128
    const float* __restrict__ dtb,   // ld 1024
    const float* __restrict__ xc,    // ld 32
    const float* __restrict__ A_log, // [16]
    float* __restrict__ ybase,       // PARTIAL ? ypart[16][B*T*D] : y (pre-zeroed)
    int T)
{
  const int b = blockIdx.x >> 4;
  const int s = blockIdx.x & 15;
  const int d0 = threadIdx.x << 2;
  const int lane = threadIdx.x & 63;
  const int wid = threadIdx.x >> 6;   // 0..3

  __shared__ __align__(16) float red[3][4][4];  // [buf][wave][{Podd_r,Podd_i,Pev_r,Pev_i}]

  const float a_s = expf(A_log[s]);
  const float phase = (float)(6.283185307179586 * (double)s / 16.0);
  float d_r = 0.01f * cosf(phase);
  float d_i = 0.01f * sinf(phase);
  float h_r[4] = {0.f,0.f,0.f,0.f};
  float h_i[4] = {0.f,0.f,0.f,0.f};
  float al[4];

  const size_t rb = (size_t)b * T;
  const float* px  = xin + rb * 2048 + d0;
  const float* pdt = dtb + rb * 1024 + d0;
  const float* pB  = xp  + rb * 128 + 64 + 2 * s;
  const float* pC  = xp  + rb * 128 + 96 + 2 * s;
  const float* pxc = xc  + rb * 32 + 2 * s;
  float* py = PARTIAL ? (ybase + (size_t)s * (4 * 512 * 1024) + rb * 1024 + d0)
                      : (ybase + rb * 1024 + d0);

  // slots A=row0, B=row1, C=row2
  float4 xA = *(const float4*)px;
  float4 tA = *(const float4*)pdt;
  float2 BA = *(const float2*)pB;
  float2 CA = *(const float2*)pC;
  float2 cA = *(const float2*)pxc;
  float4 xB = *(const float4*)(px + 2048);
  float4 tB = *(const float4*)(pdt + 1024);
  float2 BB = *(const float2*)(pB + 128);
  float2 CB = *(const float2*)(pC + 128);
  float2 cB = *(const float2*)(pxc + 32);
  float4 xC = *(const float4*)(px + 2 * 2048);
  float4 tC = *(const float4*)(pdt + 2 * 1024);
  float2 BC = *(const float2*)(pB + 2 * 128);
  float2 CC = *(const float2*)(pC + 2 * 128);
  float2 cC = *(const float2*)(pxc + 2 * 32);

  // prologue ("period -1"): alpha(0) + comp(0) from h=0; write {P(-1)=0, P(0)}
  {
    float w0r, w0i;
    comp_block(tA, a_s, h_r, h_i, al, w0r, w0i);
    if (lane == 63) *(float4*)&red[0][wid][0] = make_float4(0.f, 0.f, w0r, w0i);
  }
  __syncthreads();

  // 85 triples = periods 0..254 (rows 0..509), then epilogue period 255 (rows 510,511)
  for (int it = 0; it < 85; ++it) {
    period_body<0, 0, PARTIAL>(px, pdt, pB, pC, pxc, py, a_s, lane, wid, red,
        d_r, d_i, h_r, h_i, al,
        xA, tA, BA, CA, cA,  xB, tB, BB, CB, cB,  tC);
    period_body<1, 2, PARTIAL>(px, pdt, pB, pC, pxc, py, a_s, lane, wid, red,
        d_r, d_i, h_r, h_i, al,
        xC, tC, BC, CC, cC,  xA, tA, BA, CA, cA,  tB);
    period_body<2, 4, PARTIAL>(px, pdt, pB, pC, pxc, py, a_s, lane, wid, red,
        d_r, d_i, h_r, h_i, al,
        xB, tB, BB, CB, cB,  xC, tC, BC, CC, cC,  tA);
    px += 6 * 2048; pdt += 6 * 1024; pB += 6 * 128; pC += 6 * 128; pxc += 6 * 32;
    py += 6 * 1024;
  }
  // epilogue: rows 510,511 (period index 255, 255%3==0 -> RB=0, same slot order
  // as the first triple position; its refills/extra comp are OOB-safe in-workspace)
  period_body<0, 0, PARTIAL>(px, pdt, pB, pC, pxc, py, a_s, lane, wid, red,
      d_r, d_i, h_r, h_i, al,
      xA, tA, BA, CA, cA,  xB, tB, BB, CB, cB,  tC);
}

extern "C" void kernel_launch(void* const* d_in, const int* in_sizes, int n_in,
                              void* d_out, int out_size, void* d_ws, size_t ws_size,
                              hipStream_t stream) {
  const float* x     = (const float*)d_in[0];
  const float* W_in  = (const float*)d_in[1];
  const float* W_xp  = (const float*)d_in[2];
  const float* W_dt  = (const float*)d_in[3];
  const float* b_dt  = (const float*)d_in[4];
  const float* W_out = (const float*)d_in[5];
  const float* b_out = (const float*)d_in[6];
  const float* W_res = (const float*)d_in[7];
  const float* A_log = (const float*)d_in[8];
  float* out = (float*)d_out;

  float* ws     = (float*)d_ws;
  float* siluxz = ws;                               // 2048*2048   = 4,194,304 f
  float* xp     = siluxz + (size_t)2048 * 2048;     // 2048*128    =   262,144 f
  float* dtb    = xp     + (size_t)2048 * 128;      // 2048*1024   = 2,097,152 f
  float* xc     = dtb    + (size_t)2048 * 1024;     // 2048*32     =    65,536 f
  float* ybuf   = xc     + (size_t)2048 * 32;       // 2048*1024   = 2,097,152 f
  float* ypart  = ybuf   + (size_t)2048 * 1024;     // 16*2048*1024 = 33,554,432 f

  const size_t need_bytes = ((size_t)8716288 + (size_t)33554432) * 4;  // base + ypart
  const bool use_part = ws_size >= need_bytes;

  // g1: siluxz = silu(x @ W_in.T)   M=2048 N=2048 K=1024
  gemm_wt<EPI_SILU, false><<<dim3(32, 32), 256, 0, stream>>>(
      x, 1024, nullptr, 0, W_in, 1024, nullptr, siluxz, 2048, 2048, 1024);
  // g2: xp = x_in @ W_xproj.T       N=128 K=1024
  gemm_wt<EPI_NONE, false><<<dim3(32, 2), 256, 0, stream>>>(
      siluxz, 2048, nullptr, 0, W_xp, 1024, nullptr, xp, 128, 128, 1024);
  // g3: dt = softplus(xp[:, :64] @ W_dt.T + b_dt)  N=1024 K=64
  gemm_wt<EPI_SPBIAS, false><<<dim3(32, 16), 256, 0, stream>>>(
      xp, 128, nullptr, 0, W_dt, 64, b_dt, dtb, 1024, 1024, 64);
  // g4: xc = x_in @ W_res.T         N=32 K=1024
  gemm_wt<EPI_NONE, false><<<dim3(32, 1), 256, 0, stream>>>(
      siluxz, 2048, nullptr, 0, W_res, 1024, nullptr, xc, 32, 32, 1024);

  if (use_part) {
    scan_kernel<true><<<dim3(64), dim3(256), 0, stream>>>(
        siluxz, xp, dtb, xc, A_log, ypart, 512);
    reduce_y<<<dim3(2048), 256, 0, stream>>>((const float4*)ypart, (float4*)ybuf, 524288);
  } else {
    zero_kernel<<<dim3(2048), 256, 0, stream>>>((float4*)ybuf, (2048 * 1024) / 4);
    scan_kernel<false><<<dim3(64), dim3(256), 0, stream>>>(
        siluxz, xp, dtb, xc, A_log, ybuf, 512);
  }

  // g5: out = (y * silu(z)) @ W_out.T + b_out   N=1024 K=1024
  gemm_wt<EPI_BIAS, true><<<dim3(32, 16), 256, 0, stream>>>(
      ybuf, 1024, siluxz + 1024, 2048, W_out, 1024, b_out, out, 1024, 1024, 1024);
}